// Round 1
// baseline (1724.188 us; speedup 1.0000x reference)
//
#include <hip/hip_runtime.h>

// ---- fixed problem shape ----
constexpr int NB  = 16;     // batch (clouds)
constexpr int NPT = 2048;   // points per cloud
constexpr int KK  = 20;     // kNN
constexpr int NEDGE = NB * NPT * KK;       // 655360
constexpr int C1 = 64, C2 = 128, EMB = 1024, OUT = 7;
__device__ constexpr double R1d = (double)NEDGE;       // BN1/BN2 row count
__device__ constexpr double R3d = (double)(NB * NPT);  // BN3 row count

static __device__ __forceinline__ unsigned long long ullmin(unsigned long long a, unsigned long long b) {
  return a < b ? a : b;
}

// ---------------- kNN: per (b,n) block, 20 smallest dists, tie -> lower index ----------------
__global__ __launch_bounds__(256) void knn_kernel(const float* __restrict__ pos, int* __restrict__ idxo) {
  __shared__ unsigned long long keys[NPT];
  __shared__ unsigned long long wred[4];
  int bn = blockIdx.x;
  int b = bn >> 11, n = bn & (NPT - 1);
  const float* pb = pos + (size_t)b * NPT * 3;
  int t = threadIdx.x;
  float xn = pb[n * 3], yn = pb[n * 3 + 1], zn = pb[n * 3 + 2];
  float sqn = xn * xn + yn * yn + zn * zn;
  for (int i = 0; i < NPT / 256; ++i) {
    int m = t + 256 * i;
    float xm = pb[m * 3], ym = pb[m * 3 + 1], zm = pb[m * 3 + 2];
    float sqm = xm * xm + ym * ym + zm * zm;
    float dt = xn * xm + yn * ym + zn * zm;
    float d = sqn + sqm - 2.0f * dt;
    unsigned ub = __float_as_uint(d);
    ub = (ub & 0x80000000u) ? ~ub : (ub | 0x80000000u);  // order-preserving map
    keys[m] = ((unsigned long long)ub << 32) | (unsigned long long)(unsigned)m;
  }
  __syncthreads();
  int lane = t & 63, w = t >> 6;
  for (int r = 0; r < KK; ++r) {
    unsigned long long best = ~0ull;
    #pragma unroll
    for (int i = 0; i < NPT / 256; ++i) best = ullmin(best, keys[t + 256 * i]);
    #pragma unroll
    for (int off = 32; off > 0; off >>= 1) best = ullmin(best, __shfl_down(best, off));
    if (lane == 0) wred[w] = best;
    __syncthreads();
    if (t == 0) {
      unsigned long long bb = ullmin(ullmin(wred[0], wred[1]), ullmin(wred[2], wred[3]));
      int m = (int)(bb & 0xffffffffull);
      idxo[(size_t)bn * KK + r] = m;
      keys[m] = ~0ull;
    }
    __syncthreads();
  }
}

// ---------------- edge-feature first/second moments (6 + 21 doubles) ----------------
__global__ __launch_bounds__(256) void statse_kernel(const float* __restrict__ pos, const int* __restrict__ idx,
                                                     double* __restrict__ dstats) {
  float acc[27];
  #pragma unroll
  for (int i = 0; i < 27; ++i) acc[i] = 0.f;
  int t = threadIdx.x;
  for (int e = blockIdx.x * 256 + t; e < NEDGE; e += gridDim.x * 256) {
    int bn = e / KK;
    int b = bn >> 11, n = bn & (NPT - 1);
    int j = idx[e];
    const float* pb = pos + (size_t)b * NPT * 3;
    float f[6];
    f[0] = pb[n * 3]; f[1] = pb[n * 3 + 1]; f[2] = pb[n * 3 + 2];
    f[3] = pb[j * 3] - f[0]; f[4] = pb[j * 3 + 1] - f[1]; f[5] = pb[j * 3 + 2] - f[2];
    int p = 6;
    #pragma unroll
    for (int d = 0; d < 6; ++d) acc[d] += f[d];
    #pragma unroll
    for (int d = 0; d < 6; ++d)
      #pragma unroll
      for (int q = d; q < 6; ++q) { acc[p] += f[d] * f[q]; ++p; }
  }
  __shared__ float sred[4][27];
  int lane = t & 63, w = t >> 6;
  #pragma unroll
  for (int c = 0; c < 27; ++c) {
    float v = acc[c];
    #pragma unroll
    for (int off = 32; off > 0; off >>= 1) v += __shfl_down(v, off);
    if (lane == 0) sred[w][c] = v;
  }
  __syncthreads();
  if (t < 27) {
    double s = (double)sred[0][t] + (double)sred[1][t] + (double)sred[2][t] + (double)sred[3][t];
    atomicAdd(&dstats[t], s);
  }
}

// ---------------- BN1 coeffs from moments: scale1/shift1 ----------------
__global__ void finalize1_kernel(const double* __restrict__ dstats, const float* __restrict__ W1,
                                 const float* __restrict__ b1, const float* __restrict__ g1,
                                 const float* __restrict__ be1, float* __restrict__ scale1,
                                 float* __restrict__ shift1) {
  int c = threadIdx.x;  // 64
  double m1[6], M2[6][6];
  for (int d = 0; d < 6; ++d) m1[d] = dstats[d];
  int p = 6;
  for (int d = 0; d < 6; ++d)
    for (int q = d; q < 6; ++q) { M2[d][q] = dstats[p]; M2[q][d] = dstats[p]; ++p; }
  double w[6];
  for (int d = 0; d < 6; ++d) w[d] = W1[d * C1 + c];
  double wm = 0, quad = 0;
  for (int d = 0; d < 6; ++d) wm += w[d] * m1[d];
  for (int d = 0; d < 6; ++d) {
    double s = 0;
    for (int q = 0; q < 6; ++q) s += M2[d][q] * w[q];
    quad += w[d] * s;
  }
  double bb = b1[c];
  double mean = wm / R1d + bb;
  double E2 = (quad + 2.0 * bb * wm) / R1d + bb * bb;
  double var = E2 - mean * mean;
  double sc = (double)g1[c] / sqrt(var + 1e-5);
  scale1[c] = (float)sc;
  shift1[c] = (float)((double)be1[c] - mean * sc);
}

// ---------------- pass over edges: a2 = h1@W2+b2, accumulate per-channel sum/sumsq ----------------
__global__ __launch_bounds__(256) void stats2_kernel(const float* __restrict__ pos, const int* __restrict__ idx,
    const float* __restrict__ W1, const float* __restrict__ b1,
    const float* __restrict__ scale1, const float* __restrict__ shift1,
    const float* __restrict__ W2, const float* __restrict__ b2,
    double* __restrict__ gsum, double* __restrict__ gsq) {
  __shared__ float e_lds[32 * 6];
  __shared__ float h_lds[32 * C1];
  __shared__ double dred[256];
  int t = threadIdx.x;
  int c2 = t & 127, g = t >> 7;
  float w2c[C1];
  #pragma unroll
  for (int j = 0; j < C1; ++j) w2c[j] = W2[j * C2 + c2];
  float b2c = b2[c2];
  double accs = 0.0, accq = 0.0;
  for (int tile = blockIdx.x; tile < NEDGE / 32; tile += gridDim.x) {
    if (t < 192) {
      int r = t / 6, comp = t - r * 6;
      int e = tile * 32 + r;
      int bn = e / KK;
      int b = bn >> 11, n = bn & (NPT - 1);
      int j = idx[e];
      const float* pb = pos + (size_t)b * NPT * 3;
      float v;
      if (comp < 3) v = pb[n * 3 + comp];
      else          v = pb[j * 3 + comp - 3] - pb[n * 3 + comp - 3];
      e_lds[r * 6 + comp] = v;
    }
    __syncthreads();
    #pragma unroll
    for (int i = 0; i < 8; ++i) {
      int slot = t + 256 * i;
      int r = slot >> 6, c1 = slot & 63;
      float a = b1[c1];
      #pragma unroll
      for (int d = 0; d < 6; ++d) a += e_lds[r * 6 + d] * W1[d * C1 + c1];
      a = a * scale1[c1] + shift1[c1];
      h_lds[slot] = a > 0.f ? a : 0.f;
    }
    __syncthreads();
    #pragma unroll
    for (int rr = 0; rr < 16; ++rr) {
      int r = g * 16 + rr;
      float a = b2c;
      #pragma unroll
      for (int j = 0; j < C1; ++j) a += h_lds[r * C1 + j] * w2c[j];
      accs += (double)a;
      accq += (double)a * (double)a;
    }
    __syncthreads();
  }
  dred[t] = accs; __syncthreads();
  if (g == 0) atomicAdd(&gsum[c2], dred[t] + dred[t + 128]);
  __syncthreads();
  dred[t] = accq; __syncthreads();
  if (g == 0) atomicAdd(&gsq[c2], dred[t] + dred[t + 128]);
}

__global__ void finalize2_kernel(const double* __restrict__ gsum, const double* __restrict__ gsq,
                                 const float* __restrict__ g2w, const float* __restrict__ be2,
                                 float* __restrict__ scale2, float* __restrict__ shift2) {
  int c = threadIdx.x;  // 128
  double mean = gsum[c] / R1d;
  double var = gsq[c] / R1d - mean * mean;
  double sc = (double)g2w[c] / sqrt(var + 1e-5);
  scale2[c] = (float)sc;
  shift2[c] = (float)((double)be2[c] - mean * sc);
}

// ---------------- apply BN2+ReLU, max over k -> node[B*N,128] ----------------
__global__ __launch_bounds__(256) void apply2max_kernel(const float* __restrict__ pos, const int* __restrict__ idx,
    const float* __restrict__ W1, const float* __restrict__ b1,
    const float* __restrict__ scale1, const float* __restrict__ shift1,
    const float* __restrict__ W2, const float* __restrict__ b2,
    const float* __restrict__ scale2, const float* __restrict__ shift2,
    float* __restrict__ node) {
  __shared__ float e_lds[KK * 6];
  __shared__ float h_lds[KK * C1];
  __shared__ float red[128];
  int t = threadIdx.x;
  int c2 = t & 127, g = t >> 7;
  float w2c[C1];
  #pragma unroll
  for (int j = 0; j < C1; ++j) w2c[j] = W2[j * C2 + c2];
  float b2c = b2[c2], s2 = scale2[c2], sh2 = shift2[c2];
  for (int bn = blockIdx.x; bn < NB * NPT; bn += gridDim.x) {
    if (t < KK * 6) {
      int r = t / 6, comp = t - (t / 6) * 6;
      int e = bn * KK + r;
      int b = bn >> 11, n = bn & (NPT - 1);
      int j = idx[e];
      const float* pb = pos + (size_t)b * NPT * 3;
      float v;
      if (comp < 3) v = pb[n * 3 + comp];
      else          v = pb[j * 3 + comp - 3] - pb[n * 3 + comp - 3];
      e_lds[r * 6 + comp] = v;
    }
    __syncthreads();
    #pragma unroll
    for (int i = 0; i < 5; ++i) {
      int slot = t + 256 * i;
      int r = slot >> 6, c1 = slot & 63;
      float a = b1[c1];
      #pragma unroll
      for (int d = 0; d < 6; ++d) a += e_lds[r * 6 + d] * W1[d * C1 + c1];
      a = a * scale1[c1] + shift1[c1];
      h_lds[slot] = a > 0.f ? a : 0.f;
    }
    __syncthreads();
    float m = 0.f;  // post-ReLU values are >= 0
    #pragma unroll
    for (int rr = 0; rr < 10; ++rr) {
      int r = g * 10 + rr;
      float a = b2c;
      #pragma unroll
      for (int j = 0; j < C1; ++j) a += h_lds[r * C1 + j] * w2c[j];
      float h2 = a * s2 + sh2;
      h2 = h2 > 0.f ? h2 : 0.f;
      m = m > h2 ? m : h2;
    }
    if (g == 0) red[c2] = m;
    __syncthreads();
    if (g == 1) {
      float mm = red[c2];
      mm = mm > m ? mm : m;
      node[(size_t)bn * C2 + c2] = mm;
    }
    __syncthreads();
  }
}

// ---------------- Gram matrix G2 = node^T node (128x128) + column sums ----------------
__global__ __launch_bounds__(256) void gram_kernel(const float* __restrict__ node, double* __restrict__ G2,
                                                   double* __restrict__ nodesum) {
  __shared__ float tile[64 * C2];  // 32 KiB
  int t = threadIdx.x;
  int i = t & 127, jh = t >> 7;
  float acc[64];
  #pragma unroll
  for (int u = 0; u < 64; ++u) acc[u] = 0.f;
  float csum = 0.f;
  for (int tl = blockIdx.x; tl < (NB * NPT) / 64; tl += gridDim.x) {
    float4* t4 = (float4*)tile;
    const float4* n4 = (const float4*)(node + (size_t)tl * 64 * C2);
    #pragma unroll
    for (int q = 0; q < 8; ++q) t4[t + 256 * q] = n4[t + 256 * q];
    __syncthreads();
    #pragma unroll 4
    for (int r = 0; r < 64; ++r) {
      float xi = tile[r * C2 + i];
      const float4* row4 = (const float4*)&tile[r * C2 + jh * 64];
      #pragma unroll
      for (int u4 = 0; u4 < 16; ++u4) {
        float4 v = row4[u4];
        acc[u4 * 4 + 0] += xi * v.x;
        acc[u4 * 4 + 1] += xi * v.y;
        acc[u4 * 4 + 2] += xi * v.z;
        acc[u4 * 4 + 3] += xi * v.w;
      }
    }
    if (t < 128) {
      #pragma unroll 8
      for (int r = 0; r < 64; ++r) csum += tile[r * C2 + t];
    }
    __syncthreads();
  }
  #pragma unroll
  for (int u = 0; u < 64; ++u) atomicAdd(&G2[(size_t)i * C2 + jh * 64 + u], (double)acc[u]);
  if (t < 128) atomicAdd(&nodesum[t], (double)csum);
}

// ---------------- BN3 coeffs from Gram: scale3/shift3 (one block per channel) ----------------
__global__ __launch_bounds__(128) void finalize3_kernel(const double* __restrict__ G2, const double* __restrict__ nodesum,
    const float* __restrict__ W3, const float* __restrict__ b3,
    const float* __restrict__ g3, const float* __restrict__ be3,
    float* __restrict__ scale3, float* __restrict__ shift3) {
  int c = blockIdx.x;   // 1024 channels
  int t = threadIdx.x;  // 128
  __shared__ double wsh[128];
  __shared__ double sh[128];
  double w = W3[(size_t)t * EMB + c];
  wsh[t] = w;
  __syncthreads();
  double rowdot = 0;
  for (int j = 0; j < 128; ++j) rowdot += G2[(size_t)j * C2 + t] * wsh[j];
  sh[t] = w * rowdot;
  __syncthreads();
  for (int off = 64; off > 0; off >>= 1) { if (t < off) sh[t] += sh[t + off]; __syncthreads(); }
  double quad = sh[0];
  __syncthreads();
  sh[t] = w * nodesum[t];
  __syncthreads();
  for (int off = 64; off > 0; off >>= 1) { if (t < off) sh[t] += sh[t + off]; __syncthreads(); }
  if (t == 0) {
    double wm = sh[0];
    double bb = b3[c];
    double mean = wm / R3d + bb;
    double E2 = (quad + 2.0 * bb * wm) / R3d + bb * bb;
    double var = E2 - mean * mean;
    double sc = (double)g3[c] / sqrt(var + 1e-5);
    scale3[c] = (float)sc;
    shift3[c] = (float)((double)be3[c] - mean * sc);
  }
}

// ---------------- linear1 apply + BN3 + ReLU + global max/sum pooling ----------------
__global__ __launch_bounds__(256) void apply3pool_kernel(const float* __restrict__ node,
    const float* __restrict__ W3, const float* __restrict__ b3,
    const float* __restrict__ scale3, const float* __restrict__ shift3,
    unsigned* __restrict__ pmax, float* __restrict__ psum) {
  __shared__ float tile[32 * C2];  // 16 KiB
  int rt = blockIdx.x;  // 1024 row tiles of 32 rows
  int ct = blockIdx.y;  // 2 column halves
  int t = threadIdx.x;
  int b = rt >> 6;      // 64 tiles per cloud
  int c0 = ct * 512 + t;
  int c1 = c0 + 256;
  float4* t4 = (float4*)tile;
  const float4* n4 = (const float4*)(node + (size_t)rt * 32 * C2);
  #pragma unroll
  for (int q = 0; q < 4; ++q) t4[t + 256 * q] = n4[t + 256 * q];
  __syncthreads();
  float a0[32], a1[32];
  #pragma unroll
  for (int r = 0; r < 32; ++r) { a0[r] = 0.f; a1[r] = 0.f; }
  for (int j = 0; j < 128; j += 4) {
    float w00 = W3[(size_t)j * EMB + c0], w01 = W3[(size_t)(j + 1) * EMB + c0];
    float w02 = W3[(size_t)(j + 2) * EMB + c0], w03 = W3[(size_t)(j + 3) * EMB + c0];
    float w10 = W3[(size_t)j * EMB + c1], w11 = W3[(size_t)(j + 1) * EMB + c1];
    float w12 = W3[(size_t)(j + 2) * EMB + c1], w13 = W3[(size_t)(j + 3) * EMB + c1];
    #pragma unroll
    for (int r = 0; r < 32; ++r) {
      float4 v = *(const float4*)&tile[r * C2 + j];
      a0[r] += v.x * w00 + v.y * w01 + v.z * w02 + v.w * w03;
      a1[r] += v.x * w10 + v.y * w11 + v.z * w12 + v.w * w13;
    }
  }
  float b30 = b3[c0], s30 = scale3[c0], sh30 = shift3[c0];
  float b31 = b3[c1], s31 = scale3[c1], sh31 = shift3[c1];
  float mx0 = 0.f, sm0 = 0.f, mx1 = 0.f, sm1 = 0.f;
  #pragma unroll
  for (int r = 0; r < 32; ++r) {
    float x0 = (a0[r] + b30) * s30 + sh30; x0 = x0 > 0.f ? x0 : 0.f; mx0 = mx0 > x0 ? mx0 : x0; sm0 += x0;
    float x1 = (a1[r] + b31) * s31 + sh31; x1 = x1 > 0.f ? x1 : 0.f; mx1 = mx1 > x1 ? mx1 : x1; sm1 += x1;
  }
  atomicMax(&pmax[(size_t)b * EMB + c0], __float_as_uint(mx0));
  atomicAdd(&psum[(size_t)b * EMB + c0], sm0);
  atomicMax(&pmax[(size_t)b * EMB + c1], __float_as_uint(mx1));
  atomicAdd(&psum[(size_t)b * EMB + c1], sm1);
}

// ---------------- final linear: pooled[16,2048] @ W4 + b4 -> out[16,7] ----------------
__global__ __launch_bounds__(64) void final_kernel(const unsigned* __restrict__ pmax, const float* __restrict__ psum,
    const float* __restrict__ W4, const float* __restrict__ b4, float* __restrict__ out) {
  int b = blockIdx.x, t = threadIdx.x;
  #pragma unroll
  for (int o = 0; o < OUT; ++o) {
    float acc = 0.f;
    for (int tt = t; tt < 2 * EMB; tt += 64) {
      float p = (tt < EMB) ? __uint_as_float(pmax[(size_t)b * EMB + tt])
                           : psum[(size_t)b * EMB + tt - EMB] * (1.0f / (float)NPT);
      acc += p * W4[(size_t)tt * OUT + o];
    }
    #pragma unroll
    for (int off = 32; off > 0; off >>= 1) acc += __shfl_down(acc, off);
    if (t == 0) out[b * OUT + o] = acc + b4[o];
  }
}

extern "C" void kernel_launch(void* const* d_in, const int* in_sizes, int n_in,
                              void* d_out, int out_size, void* d_ws, size_t ws_size,
                              hipStream_t stream) {
  const float* pos = (const float*)d_in[0];
  const float* W1 = (const float*)d_in[1];  const float* b1 = (const float*)d_in[2];
  const float* g1 = (const float*)d_in[3];  const float* be1 = (const float*)d_in[4];
  const float* W2 = (const float*)d_in[5];  const float* b2 = (const float*)d_in[6];
  const float* g2 = (const float*)d_in[7];  const float* be2 = (const float*)d_in[8];
  const float* W3 = (const float*)d_in[9];  const float* b3 = (const float*)d_in[10];
  const float* g3 = (const float*)d_in[11]; const float* be3 = (const float*)d_in[12];
  const float* W4 = (const float*)d_in[13]; const float* b4 = (const float*)d_in[14];
  float* out = (float*)d_out;

  char* ws = (char*)d_ws;
  int* idx = (int*)ws;                                   // 655360 ints = 2.5 MiB
  float* node = (float*)(ws + (size_t)NEDGE * 4);        // 32768*128 f32 = 16 MiB
  char* accbase = ws + (size_t)NEDGE * 4 + (size_t)NB * NPT * C2 * 4;

  double* dstats  = (double*)accbase;     // 27
  double* gsum2   = dstats + 27;          // 128
  double* gsq2    = gsum2 + 128;          // 128
  double* nodesum = gsq2 + 128;           // 128
  double* G2      = nodesum + 128;        // 16384
  float* scale1 = (float*)(G2 + 16384);
  float* shift1 = scale1 + C1;
  float* scale2 = shift1 + C1;
  float* shift2 = scale2 + C2;
  float* scale3 = shift2 + C2;
  float* shift3 = scale3 + EMB;
  float* pmaxf  = shift3 + EMB;           // 16*1024
  float* psum   = pmaxf + NB * EMB;       // 16*1024
  size_t accbytes = (size_t)((char*)(psum + NB * EMB) - accbase);

  hipMemsetAsync(accbase, 0, accbytes, stream);

  knn_kernel<<<NB * NPT, 256, 0, stream>>>(pos, idx);
  statse_kernel<<<512, 256, 0, stream>>>(pos, idx, dstats);
  finalize1_kernel<<<1, 64, 0, stream>>>(dstats, W1, b1, g1, be1, scale1, shift1);
  stats2_kernel<<<512, 256, 0, stream>>>(pos, idx, W1, b1, scale1, shift1, W2, b2, gsum2, gsq2);
  finalize2_kernel<<<1, 128, 0, stream>>>(gsum2, gsq2, g2, be2, scale2, shift2);
  apply2max_kernel<<<4096, 256, 0, stream>>>(pos, idx, W1, b1, scale1, shift1, W2, b2, scale2, shift2, node);
  gram_kernel<<<256, 256, 0, stream>>>(node, G2, nodesum);
  finalize3_kernel<<<EMB, 128, 0, stream>>>(G2, nodesum, W3, b3, g3, be3, scale3, shift3);
  apply3pool_kernel<<<dim3(1024, 2), 256, 0, stream>>>(node, W3, b3, scale3, shift3, (unsigned*)pmaxf, psum);
  final_kernel<<<NB, 64, 0, stream>>>((const unsigned*)pmaxf, psum, W4, b4, out);
}

// Round 2
// 996.685 us; speedup vs baseline: 1.7299x; 1.7299x over previous
//
#include <hip/hip_runtime.h>
#include <float.h>

// ---- fixed problem shape ----
constexpr int NB  = 16;     // batch (clouds)
constexpr int NPT = 2048;   // points per cloud
constexpr int KK  = 20;     // kNN
constexpr int NEDGE = NB * NPT * KK;       // 655360
constexpr int C1 = 64, C2 = 128, EMB = 1024, OUT = 7;
__device__ constexpr double R1d = (double)NEDGE;       // BN1/BN2 row count
__device__ constexpr double R3d = (double)(NB * NPT);  // BN3 row count
constexpr unsigned long long INF64 = ~0ull;

// ---------------- kNN v2: one wave per query, keys in registers, threshold tournament --------
// Packed key = (order-preserving dist bits << 32) | point index  -> all keys distinct.
// Round r: winner = min{key >= T}; T = winner+1. 20 rounds give the 20 smallest
// (ties -> lower index, matching jax.lax.top_k on -dist).
__global__ __launch_bounds__(256) void knn_kernel(const float* __restrict__ pos, int* __restrict__ idxo) {
  int t = threadIdx.x;
  int lane = t & 63, w = t >> 6;
  int bn = blockIdx.x * 4 + w;            // 8192 blocks x 4 waves = 32768 queries
  int b = bn >> 11, n = bn & (NPT - 1);
  const float* pb = pos + (size_t)b * NPT * 3;
  float xn = pb[n * 3], yn = pb[n * 3 + 1], zn = pb[n * 3 + 2];
  float sqn = xn * xn + yn * yn + zn * zn;

  unsigned long long key[32];
  #pragma unroll 8
  for (int i = 0; i < 32; ++i) {
    int m = i * 64 + lane;
    float xm = pb[m * 3], ym = pb[m * 3 + 1], zm = pb[m * 3 + 2];
    float sqm = xm * xm + ym * ym + zm * zm;
    float dt = xn * xm + yn * ym + zn * zm;
    float d = sqn + sqm - 2.0f * dt;
    unsigned ub = __float_as_uint(d);
    ub = (ub & 0x80000000u) ? ~ub : (ub | 0x80000000u);  // order-preserving map
    key[i] = ((unsigned long long)ub << 32) | (unsigned long long)(unsigned)m;
  }

  unsigned long long T = 0;
  int myidx = 0;
  for (int r = 0; r < KK; ++r) {
    // local predicated min over 32 register keys (static-index tree)
    unsigned long long t0[16];
    #pragma unroll
    for (int i = 0; i < 16; ++i) {
      unsigned long long a = key[2 * i]     >= T ? key[2 * i]     : INF64;
      unsigned long long c = key[2 * i + 1] >= T ? key[2 * i + 1] : INF64;
      t0[i] = a < c ? a : c;
    }
    #pragma unroll
    for (int s = 8; s > 0; s >>= 1)
      #pragma unroll
      for (int i = 0; i < 8; ++i)
        if (i < s) t0[i] = t0[i] < t0[i + s] ? t0[i] : t0[i + s];
    unsigned long long best = t0[0];
    // wave butterfly min
    #pragma unroll
    for (int off = 32; off > 0; off >>= 1) {
      unsigned long long o = (unsigned long long)__shfl_xor((long long)best, off, 64);
      best = best < o ? best : o;
    }
    if (lane == r) myidx = (int)(unsigned)(best & 0xffffffffull);
    T = best + 1;
  }
  if (lane < KK) idxo[(size_t)bn * KK + lane] = myidx;
}

// ---------------- edge-feature first/second moments (6 + 21 doubles) ----------------
__global__ __launch_bounds__(256) void statse_kernel(const float* __restrict__ pos, const int* __restrict__ idx,
                                                     double* __restrict__ dstats) {
  float acc[27];
  #pragma unroll
  for (int i = 0; i < 27; ++i) acc[i] = 0.f;
  int t = threadIdx.x;
  for (int e = blockIdx.x * 256 + t; e < NEDGE; e += gridDim.x * 256) {
    int bn = e / KK;
    int b = bn >> 11, n = bn & (NPT - 1);
    int j = idx[e];
    const float* pb = pos + (size_t)b * NPT * 3;
    float f[6];
    f[0] = pb[n * 3]; f[1] = pb[n * 3 + 1]; f[2] = pb[n * 3 + 2];
    f[3] = pb[j * 3] - f[0]; f[4] = pb[j * 3 + 1] - f[1]; f[5] = pb[j * 3 + 2] - f[2];
    int p = 6;
    #pragma unroll
    for (int d = 0; d < 6; ++d) acc[d] += f[d];
    #pragma unroll
    for (int d = 0; d < 6; ++d)
      #pragma unroll
      for (int q = d; q < 6; ++q) { acc[p] += f[d] * f[q]; ++p; }
  }
  __shared__ float sred[4][27];
  int lane = t & 63, w = t >> 6;
  #pragma unroll
  for (int c = 0; c < 27; ++c) {
    float v = acc[c];
    #pragma unroll
    for (int off = 32; off > 0; off >>= 1) v += __shfl_down(v, off);
    if (lane == 0) sred[w][c] = v;
  }
  __syncthreads();
  if (t < 27) {
    double s = (double)sred[0][t] + (double)sred[1][t] + (double)sred[2][t] + (double)sred[3][t];
    atomicAdd(&dstats[t], s);
  }
}

// ---------------- BN1 coeffs from moments: scale1/shift1 ----------------
__global__ void finalize1_kernel(const double* __restrict__ dstats, const float* __restrict__ W1,
                                 const float* __restrict__ b1, const float* __restrict__ g1,
                                 const float* __restrict__ be1, float* __restrict__ scale1,
                                 float* __restrict__ shift1) {
  int c = threadIdx.x;  // 64
  double m1[6], M2[6][6];
  for (int d = 0; d < 6; ++d) m1[d] = dstats[d];
  int p = 6;
  for (int d = 0; d < 6; ++d)
    for (int q = d; q < 6; ++q) { M2[d][q] = dstats[p]; M2[q][d] = dstats[p]; ++p; }
  double w[6];
  for (int d = 0; d < 6; ++d) w[d] = W1[d * C1 + c];
  double wm = 0, quad = 0;
  for (int d = 0; d < 6; ++d) wm += w[d] * m1[d];
  for (int d = 0; d < 6; ++d) {
    double s = 0;
    for (int q = 0; q < 6; ++q) s += M2[d][q] * w[q];
    quad += w[d] * s;
  }
  double bb = b1[c];
  double mean = wm / R1d + bb;
  double E2 = (quad + 2.0 * bb * wm) / R1d + bb * bb;
  double var = E2 - mean * mean;
  double sc = (double)g1[c] / sqrt(var + 1e-5);
  scale1[c] = (float)sc;
  shift1[c] = (float)((double)be1[c] - mean * sc);
}

// ---------------- fused: a2 pass -> BN2 stats + per-node max/min of a2 ----------------
__global__ __launch_bounds__(256) void edge2_kernel(const float* __restrict__ pos, const int* __restrict__ idx,
    const float* __restrict__ W1, const float* __restrict__ b1,
    const float* __restrict__ scale1, const float* __restrict__ shift1,
    const float* __restrict__ W2, const float* __restrict__ b2,
    float* __restrict__ amax, float* __restrict__ amin,
    double* __restrict__ gsum, double* __restrict__ gsq) {
  __shared__ float e_lds[KK * 6];
  __shared__ float h_lds[KK * C1];
  __shared__ float redmx[128];
  __shared__ float redmn[128];
  __shared__ double dred[256];
  int t = threadIdx.x;
  int c2 = t & 127, g = t >> 7;
  float w2c[C1];
  #pragma unroll
  for (int j = 0; j < C1; ++j) w2c[j] = W2[j * C2 + c2];
  float b2c = b2[c2];
  double accs = 0.0, accq = 0.0;
  for (int bn = blockIdx.x; bn < NB * NPT; bn += gridDim.x) {
    if (t < KK * 6) {
      int r = t / 6, comp = t - (t / 6) * 6;
      int e = bn * KK + r;
      int b = bn >> 11, n = bn & (NPT - 1);
      int j = idx[e];
      const float* pb = pos + (size_t)b * NPT * 3;
      float v;
      if (comp < 3) v = pb[n * 3 + comp];
      else          v = pb[j * 3 + comp - 3] - pb[n * 3 + comp - 3];
      e_lds[r * 6 + comp] = v;
    }
    __syncthreads();
    #pragma unroll
    for (int i = 0; i < 5; ++i) {
      int slot = t + 256 * i;
      int r = slot >> 6, c1 = slot & 63;
      float a = b1[c1];
      #pragma unroll
      for (int d = 0; d < 6; ++d) a += e_lds[r * 6 + d] * W1[d * C1 + c1];
      a = a * scale1[c1] + shift1[c1];
      h_lds[slot] = a > 0.f ? a : 0.f;
    }
    __syncthreads();
    float mx = -FLT_MAX, mn = FLT_MAX;
    #pragma unroll
    for (int rr = 0; rr < 10; ++rr) {
      int r = g * 10 + rr;
      float a = b2c;
      #pragma unroll
      for (int j = 0; j < C1; ++j) a += h_lds[r * C1 + j] * w2c[j];
      accs += (double)a;
      accq += (double)a * (double)a;
      mx = mx > a ? mx : a;
      mn = mn < a ? mn : a;
    }
    if (g == 0) { redmx[c2] = mx; redmn[c2] = mn; }
    __syncthreads();
    if (g == 1) {
      float fx = redmx[c2], fn = redmn[c2];
      fx = fx > mx ? fx : mx;
      fn = fn < mn ? fn : mn;
      amax[(size_t)bn * C2 + c2] = fx;
      amin[(size_t)bn * C2 + c2] = fn;
    }
    __syncthreads();
  }
  dred[t] = accs; __syncthreads();
  if (g == 0) atomicAdd(&gsum[c2], dred[t] + dred[t + 128]);
  __syncthreads();
  dred[t] = accq; __syncthreads();
  if (g == 0) atomicAdd(&gsq[c2], dred[t] + dred[t + 128]);
}

__global__ void finalize2_kernel(const double* __restrict__ gsum, const double* __restrict__ gsq,
                                 const float* __restrict__ g2w, const float* __restrict__ be2,
                                 float* __restrict__ scale2, float* __restrict__ shift2) {
  int c = threadIdx.x;  // 128
  double mean = gsum[c] / R1d;
  double var = gsq[c] / R1d - mean * mean;
  double sc = (double)g2w[c] / sqrt(var + 1e-5);
  scale2[c] = (float)sc;
  shift2[c] = (float)((double)be2[c] - mean * sc);
}

// ---------------- BN2 apply (elementwise, in-place into amax -> node) ----------------
__global__ __launch_bounds__(256) void bn2node_kernel(float* __restrict__ amax, const float* __restrict__ amin,
                                                      const float* __restrict__ scale2, const float* __restrict__ shift2) {
  int i = blockIdx.x * 256 + threadIdx.x;   // float4 index, 1048576 total
  float4 A = ((const float4*)amax)[i];
  float4 N = ((const float4*)amin)[i];
  int c4 = i & 31;                           // channel quad
  float4 S = ((const float4*)scale2)[c4];
  float4 H = ((const float4*)shift2)[c4];
  float4 o;
  o.x = (S.x >= 0.f ? A.x : N.x) * S.x + H.x; o.x = o.x > 0.f ? o.x : 0.f;
  o.y = (S.y >= 0.f ? A.y : N.y) * S.y + H.y; o.y = o.y > 0.f ? o.y : 0.f;
  o.z = (S.z >= 0.f ? A.z : N.z) * S.z + H.z; o.z = o.z > 0.f ? o.z : 0.f;
  o.w = (S.w >= 0.f ? A.w : N.w) * S.w + H.w; o.w = o.w > 0.f ? o.w : 0.f;
  ((float4*)amax)[i] = o;
}

// ---------------- Gram matrix G2 = node^T node (128x128) + column sums ----------------
__global__ __launch_bounds__(256) void gram_kernel(const float* __restrict__ node, double* __restrict__ G2,
                                                   double* __restrict__ nodesum) {
  __shared__ float tile[64 * C2];  // 32 KiB
  int t = threadIdx.x;
  int i = t & 127, jh = t >> 7;
  float acc[64];
  #pragma unroll
  for (int u = 0; u < 64; ++u) acc[u] = 0.f;
  float csum = 0.f;
  for (int tl = blockIdx.x; tl < (NB * NPT) / 64; tl += gridDim.x) {
    float4* t4 = (float4*)tile;
    const float4* n4 = (const float4*)(node + (size_t)tl * 64 * C2);
    #pragma unroll
    for (int q = 0; q < 8; ++q) t4[t + 256 * q] = n4[t + 256 * q];
    __syncthreads();
    #pragma unroll 4
    for (int r = 0; r < 64; ++r) {
      float xi = tile[r * C2 + i];
      const float4* row4 = (const float4*)&tile[r * C2 + jh * 64];
      #pragma unroll
      for (int u4 = 0; u4 < 16; ++u4) {
        float4 v = row4[u4];
        acc[u4 * 4 + 0] += xi * v.x;
        acc[u4 * 4 + 1] += xi * v.y;
        acc[u4 * 4 + 2] += xi * v.z;
        acc[u4 * 4 + 3] += xi * v.w;
      }
    }
    if (t < 128) {
      #pragma unroll 8
      for (int r = 0; r < 64; ++r) csum += tile[r * C2 + t];
    }
    __syncthreads();
  }
  #pragma unroll
  for (int u = 0; u < 64; ++u) atomicAdd(&G2[(size_t)i * C2 + jh * 64 + u], (double)acc[u]);
  if (t < 128) atomicAdd(&nodesum[t], (double)csum);
}

// ---------------- BN3 coeffs from Gram: scale3/shift3 (one block per channel) ----------------
__global__ __launch_bounds__(128) void finalize3_kernel(const double* __restrict__ G2, const double* __restrict__ nodesum,
    const float* __restrict__ W3, const float* __restrict__ b3,
    const float* __restrict__ g3, const float* __restrict__ be3,
    float* __restrict__ scale3, float* __restrict__ shift3) {
  int c = blockIdx.x;   // 1024 channels
  int t = threadIdx.x;  // 128
  __shared__ double wsh[128];
  __shared__ double sh[128];
  double w = W3[(size_t)t * EMB + c];
  wsh[t] = w;
  __syncthreads();
  double rowdot = 0;
  for (int j = 0; j < 128; ++j) rowdot += G2[(size_t)j * C2 + t] * wsh[j];
  sh[t] = w * rowdot;
  __syncthreads();
  for (int off = 64; off > 0; off >>= 1) { if (t < off) sh[t] += sh[t + off]; __syncthreads(); }
  double quad = sh[0];
  __syncthreads();
  sh[t] = w * nodesum[t];
  __syncthreads();
  for (int off = 64; off > 0; off >>= 1) { if (t < off) sh[t] += sh[t + off]; __syncthreads(); }
  if (t == 0) {
    double wm = sh[0];
    double bb = b3[c];
    double mean = wm / R3d + bb;
    double E2 = (quad + 2.0 * bb * wm) / R3d + bb * bb;
    double var = E2 - mean * mean;
    double sc = (double)g3[c] / sqrt(var + 1e-5);
    scale3[c] = (float)sc;
    shift3[c] = (float)((double)be3[c] - mean * sc);
  }
}

// ---------------- linear1 apply + BN3 + ReLU + global max/sum pooling ----------------
__global__ __launch_bounds__(256) void apply3pool_kernel(const float* __restrict__ node,
    const float* __restrict__ W3, const float* __restrict__ b3,
    const float* __restrict__ scale3, const float* __restrict__ shift3,
    unsigned* __restrict__ pmax, float* __restrict__ psum) {
  __shared__ float tile[32 * C2];  // 16 KiB
  int rt = blockIdx.x;  // 1024 row tiles of 32 rows
  int ct = blockIdx.y;  // 2 column halves
  int t = threadIdx.x;
  int b = rt >> 6;      // 64 tiles per cloud
  int c0 = ct * 512 + t;
  int c1 = c0 + 256;
  float4* t4 = (float4*)tile;
  const float4* n4 = (const float4*)(node + (size_t)rt * 32 * C2);
  #pragma unroll
  for (int q = 0; q < 4; ++q) t4[t + 256 * q] = n4[t + 256 * q];
  __syncthreads();
  float a0[32], a1[32];
  #pragma unroll
  for (int r = 0; r < 32; ++r) { a0[r] = 0.f; a1[r] = 0.f; }
  for (int j = 0; j < 128; j += 4) {
    float w00 = W3[(size_t)j * EMB + c0], w01 = W3[(size_t)(j + 1) * EMB + c0];
    float w02 = W3[(size_t)(j + 2) * EMB + c0], w03 = W3[(size_t)(j + 3) * EMB + c0];
    float w10 = W3[(size_t)j * EMB + c1], w11 = W3[(size_t)(j + 1) * EMB + c1];
    float w12 = W3[(size_t)(j + 2) * EMB + c1], w13 = W3[(size_t)(j + 3) * EMB + c1];
    #pragma unroll
    for (int r = 0; r < 32; ++r) {
      float4 v = *(const float4*)&tile[r * C2 + j];
      a0[r] += v.x * w00 + v.y * w01 + v.z * w02 + v.w * w03;
      a1[r] += v.x * w10 + v.y * w11 + v.z * w12 + v.w * w13;
    }
  }
  float b30 = b3[c0], s30 = scale3[c0], sh30 = shift3[c0];
  float b31 = b3[c1], s31 = scale3[c1], sh31 = shift3[c1];
  float mx0 = 0.f, sm0 = 0.f, mx1 = 0.f, sm1 = 0.f;
  #pragma unroll
  for (int r = 0; r < 32; ++r) {
    float x0 = (a0[r] + b30) * s30 + sh30; x0 = x0 > 0.f ? x0 : 0.f; mx0 = mx0 > x0 ? mx0 : x0; sm0 += x0;
    float x1 = (a1[r] + b31) * s31 + sh31; x1 = x1 > 0.f ? x1 : 0.f; mx1 = mx1 > x1 ? mx1 : x1; sm1 += x1;
  }
  atomicMax(&pmax[(size_t)b * EMB + c0], __float_as_uint(mx0));
  atomicAdd(&psum[(size_t)b * EMB + c0], sm0);
  atomicMax(&pmax[(size_t)b * EMB + c1], __float_as_uint(mx1));
  atomicAdd(&psum[(size_t)b * EMB + c1], sm1);
}

// ---------------- final linear: pooled[16,2048] @ W4 + b4 -> out[16,7] ----------------
__global__ __launch_bounds__(64) void final_kernel(const unsigned* __restrict__ pmax, const float* __restrict__ psum,
    const float* __restrict__ W4, const float* __restrict__ b4, float* __restrict__ out) {
  int b = blockIdx.x, t = threadIdx.x;
  #pragma unroll
  for (int o = 0; o < OUT; ++o) {
    float acc = 0.f;
    for (int tt = t; tt < 2 * EMB; tt += 64) {
      float p = (tt < EMB) ? __uint_as_float(pmax[(size_t)b * EMB + tt])
                           : psum[(size_t)b * EMB + tt - EMB] * (1.0f / (float)NPT);
      acc += p * W4[(size_t)tt * OUT + o];
    }
    #pragma unroll
    for (int off = 32; off > 0; off >>= 1) acc += __shfl_down(acc, off);
    if (t == 0) out[b * OUT + o] = acc + b4[o];
  }
}

extern "C" void kernel_launch(void* const* d_in, const int* in_sizes, int n_in,
                              void* d_out, int out_size, void* d_ws, size_t ws_size,
                              hipStream_t stream) {
  const float* pos = (const float*)d_in[0];
  const float* W1 = (const float*)d_in[1];  const float* b1 = (const float*)d_in[2];
  const float* g1 = (const float*)d_in[3];  const float* be1 = (const float*)d_in[4];
  const float* W2 = (const float*)d_in[5];  const float* b2 = (const float*)d_in[6];
  const float* g2 = (const float*)d_in[7];  const float* be2 = (const float*)d_in[8];
  const float* W3 = (const float*)d_in[9];  const float* b3 = (const float*)d_in[10];
  const float* g3 = (const float*)d_in[11]; const float* be3 = (const float*)d_in[12];
  const float* W4 = (const float*)d_in[13]; const float* b4 = (const float*)d_in[14];
  float* out = (float*)d_out;

  char* ws = (char*)d_ws;
  int* idx = (int*)ws;                                      // 655360 ints = 2.5 MiB
  float* amax = (float*)(ws + (size_t)NEDGE * 4);           // 32768*128 f32 = 16 MiB (becomes node)
  float* amin = amax + (size_t)NB * NPT * C2;               // 16 MiB
  char* accbase = (char*)(amin + (size_t)NB * NPT * C2);

  double* dstats  = (double*)accbase;     // 27
  double* gsum2   = dstats + 27;          // 128
  double* gsq2    = gsum2 + 128;          // 128
  double* nodesum = gsq2 + 128;           // 128
  double* G2      = nodesum + 128;        // 16384
  float* scale1 = (float*)(G2 + 16384);
  float* shift1 = scale1 + C1;
  float* scale2 = shift1 + C1;
  float* shift2 = scale2 + C2;
  float* scale3 = shift2 + C2;
  float* shift3 = scale3 + EMB;
  float* pmaxf  = shift3 + EMB;           // 16*1024
  float* psum   = pmaxf + NB * EMB;       // 16*1024
  size_t accbytes = (size_t)((char*)(psum + NB * EMB) - accbase);

  hipMemsetAsync(accbase, 0, accbytes, stream);

  knn_kernel<<<NB * NPT / 4, 256, 0, stream>>>(pos, idx);
  statse_kernel<<<512, 256, 0, stream>>>(pos, idx, dstats);
  finalize1_kernel<<<1, 64, 0, stream>>>(dstats, W1, b1, g1, be1, scale1, shift1);
  edge2_kernel<<<4096, 256, 0, stream>>>(pos, idx, W1, b1, scale1, shift1, W2, b2, amax, amin, gsum2, gsq2);
  finalize2_kernel<<<1, 128, 0, stream>>>(gsum2, gsq2, g2, be2, scale2, shift2);
  bn2node_kernel<<<4096, 256, 0, stream>>>(amax, amin, scale2, shift2);
  gram_kernel<<<256, 256, 0, stream>>>(amax /*node*/, G2, nodesum);
  finalize3_kernel<<<EMB, 128, 0, stream>>>(G2, nodesum, W3, b3, g3, be3, scale3, shift3);
  apply3pool_kernel<<<dim3(1024, 2), 256, 0, stream>>>(amax /*node*/, W3, b3, scale3, shift3, (unsigned*)pmaxf, psum);
  final_kernel<<<NB, 64, 0, stream>>>((const unsigned*)pmaxf, psum, W4, b4, out);
}

// Round 4
// 824.196 us; speedup vs baseline: 2.0920x; 1.2093x over previous
//
#include <hip/hip_runtime.h>
#include <hip/hip_fp16.h>
#include <float.h>

// ---- fixed problem shape ----
constexpr int NB  = 16;     // batch (clouds)
constexpr int NPT = 2048;   // points per cloud
constexpr int KK  = 20;     // kNN
constexpr int NEDGE = NB * NPT * KK;       // 655360
constexpr int C1 = 64, C2 = 128, EMB = 1024, OUT = 7;
constexpr int NNODE = NB * NPT;            // 32768
constexpr int EDGE2_GRID = 4096;
constexpr int GRAM_GRID = 128;
constexpr int GRAM_ELEMS = C2 * C2 + C2;   // 16512 (Gram + colsum)
__device__ constexpr double R1d = (double)NEDGE;       // BN1/BN2 row count
__device__ constexpr double R3d = (double)(NB * NPT);  // BN3 row count
constexpr unsigned long long INF64 = ~0ull;

// ---------------- kNN: one wave per query, keys in registers, threshold tournament --------
__global__ __launch_bounds__(256) void knn_kernel(const float* __restrict__ pos, unsigned short* __restrict__ idxo) {
  int t = threadIdx.x;
  int lane = t & 63, w = t >> 6;
  int bn = blockIdx.x * 4 + w;            // 8192 blocks x 4 waves = 32768 queries
  int b = bn >> 11, n = bn & (NPT - 1);
  const float* pb = pos + (size_t)b * NPT * 3;
  float xn = pb[n * 3], yn = pb[n * 3 + 1], zn = pb[n * 3 + 2];
  float sqn = xn * xn + yn * yn + zn * zn;

  unsigned long long key[32];
  #pragma unroll 8
  for (int i = 0; i < 32; ++i) {
    int m = i * 64 + lane;
    float xm = pb[m * 3], ym = pb[m * 3 + 1], zm = pb[m * 3 + 2];
    float sqm = xm * xm + ym * ym + zm * zm;
    float dt = xn * xm + yn * ym + zn * zm;
    float d = sqn + sqm - 2.0f * dt;
    unsigned ub = __float_as_uint(d);
    ub = (ub & 0x80000000u) ? ~ub : (ub | 0x80000000u);  // order-preserving map
    key[i] = ((unsigned long long)ub << 32) | (unsigned long long)(unsigned)m;
  }

  unsigned long long T = 0;
  int myidx = 0;
  for (int r = 0; r < KK; ++r) {
    unsigned long long t0[16];
    #pragma unroll
    for (int i = 0; i < 16; ++i) {
      unsigned long long a = key[2 * i]     >= T ? key[2 * i]     : INF64;
      unsigned long long c = key[2 * i + 1] >= T ? key[2 * i + 1] : INF64;
      t0[i] = a < c ? a : c;
    }
    #pragma unroll
    for (int s = 8; s > 0; s >>= 1)
      #pragma unroll
      for (int i = 0; i < 8; ++i)
        if (i < s) t0[i] = t0[i] < t0[i + s] ? t0[i] : t0[i + s];
    unsigned long long best = t0[0];
    #pragma unroll
    for (int off = 32; off > 0; off >>= 1) {
      unsigned long long o = (unsigned long long)__shfl_xor((long long)best, off, 64);
      best = best < o ? best : o;
    }
    if (lane == r) myidx = (int)(unsigned)(best & 0xffffffffull);
    T = best + 1;
  }
  if (lane < KK) idxo[(size_t)bn * KK + lane] = (unsigned short)myidx;
}

// ---------------- edge-feature first/second moments (6 + 21 doubles) ----------------
__global__ __launch_bounds__(256) void statse_kernel(const float* __restrict__ pos, const unsigned short* __restrict__ idx,
                                                     double* __restrict__ dstats) {
  float acc[27];
  #pragma unroll
  for (int i = 0; i < 27; ++i) acc[i] = 0.f;
  int t = threadIdx.x;
  for (int e = blockIdx.x * 256 + t; e < NEDGE; e += gridDim.x * 256) {
    int bn = e / KK;
    int b = bn >> 11, n = bn & (NPT - 1);
    int j = idx[e];
    const float* pb = pos + (size_t)b * NPT * 3;
    float f[6];
    f[0] = pb[n * 3]; f[1] = pb[n * 3 + 1]; f[2] = pb[n * 3 + 2];
    f[3] = pb[j * 3] - f[0]; f[4] = pb[j * 3 + 1] - f[1]; f[5] = pb[j * 3 + 2] - f[2];
    int p = 6;
    #pragma unroll
    for (int d = 0; d < 6; ++d) acc[d] += f[d];
    #pragma unroll
    for (int d = 0; d < 6; ++d)
      #pragma unroll
      for (int q = d; q < 6; ++q) { acc[p] += f[d] * f[q]; ++p; }
  }
  __shared__ float sred[4][27];
  int lane = t & 63, w = t >> 6;
  #pragma unroll
  for (int c = 0; c < 27; ++c) {
    float v = acc[c];
    #pragma unroll
    for (int off = 32; off > 0; off >>= 1) v += __shfl_down(v, off);
    if (lane == 0) sred[w][c] = v;
  }
  __syncthreads();
  if (t < 27) {
    double s = (double)sred[0][t] + (double)sred[1][t] + (double)sred[2][t] + (double)sred[3][t];
    atomicAdd(&dstats[t], s);
  }
}

// ---------------- BN1 coeffs from moments ----------------
__global__ void finalize1_kernel(const double* __restrict__ dstats, const float* __restrict__ W1,
                                 const float* __restrict__ b1, const float* __restrict__ g1,
                                 const float* __restrict__ be1, float* __restrict__ scale1,
                                 float* __restrict__ shift1) {
  int c = threadIdx.x;  // 64
  double m1[6], M2[6][6];
  for (int d = 0; d < 6; ++d) m1[d] = dstats[d];
  int p = 6;
  for (int d = 0; d < 6; ++d)
    for (int q = d; q < 6; ++q) { M2[d][q] = dstats[p]; M2[q][d] = dstats[p]; ++p; }
  double w[6];
  for (int d = 0; d < 6; ++d) w[d] = W1[d * C1 + c];
  double wm = 0, quad = 0;
  for (int d = 0; d < 6; ++d) wm += w[d] * m1[d];
  for (int d = 0; d < 6; ++d) {
    double s = 0;
    for (int q = 0; q < 6; ++q) s += M2[d][q] * w[q];
    quad += w[d] * s;
  }
  double bb = b1[c];
  double mean = wm / R1d + bb;
  double E2 = (quad + 2.0 * bb * wm) / R1d + bb * bb;
  double var = E2 - mean * mean;
  double sc = (double)g1[c] / sqrt(var + 1e-5);
  scale1[c] = (float)sc;
  shift1[c] = (float)((double)be1[c] - mean * sc);
}

// ---------------- fused edge pass: BN2 partial stats + per-node (max,min) of a2 as half2 ----------------
__global__ __launch_bounds__(256) void edge2_kernel(const float* __restrict__ pos, const unsigned short* __restrict__ idx,
    const float* __restrict__ W1, const float* __restrict__ b1,
    const float* __restrict__ scale1, const float* __restrict__ shift1,
    const float* __restrict__ W2, const float* __restrict__ b2,
    __half2* __restrict__ am, double* __restrict__ part) {
  __shared__ float e_lds[KK * 6];
  __shared__ float h_lds[KK * C1];
  __shared__ float redmx[128];
  __shared__ float redmn[128];
  __shared__ double dred[256];
  int t = threadIdx.x;
  int c2 = t & 127, g = t >> 7;
  float w2c[C1];
  #pragma unroll
  for (int j = 0; j < C1; ++j) w2c[j] = W2[j * C2 + c2];
  float b2c = b2[c2];
  double accs = 0.0, accq = 0.0;
  for (int bn = blockIdx.x; bn < NB * NPT; bn += gridDim.x) {
    if (t < KK * 6) {
      int r = t / 6, comp = t - (t / 6) * 6;
      int e = bn * KK + r;
      int b = bn >> 11, n = bn & (NPT - 1);
      int j = idx[e];
      const float* pb = pos + (size_t)b * NPT * 3;
      float v;
      if (comp < 3) v = pb[n * 3 + comp];
      else          v = pb[j * 3 + comp - 3] - pb[n * 3 + comp - 3];
      e_lds[r * 6 + comp] = v;
    }
    __syncthreads();
    #pragma unroll
    for (int i = 0; i < 5; ++i) {
      int slot = t + 256 * i;
      int r = slot >> 6, c1 = slot & 63;
      float a = b1[c1];
      #pragma unroll
      for (int d = 0; d < 6; ++d) a += e_lds[r * 6 + d] * W1[d * C1 + c1];
      a = a * scale1[c1] + shift1[c1];
      h_lds[slot] = a > 0.f ? a : 0.f;
    }
    __syncthreads();
    float mx = -FLT_MAX, mn = FLT_MAX;
    #pragma unroll
    for (int rr = 0; rr < 10; ++rr) {
      int r = g * 10 + rr;
      float a = b2c;
      #pragma unroll
      for (int j = 0; j < C1; ++j) a += h_lds[r * C1 + j] * w2c[j];
      accs += (double)a;
      accq += (double)a * (double)a;
      mx = mx > a ? mx : a;
      mn = mn < a ? mn : a;
    }
    if (g == 0) { redmx[c2] = mx; redmn[c2] = mn; }
    __syncthreads();
    if (g == 1) {
      float fx = redmx[c2], fn = redmn[c2];
      fx = fx > mx ? fx : mx;
      fn = fn < mn ? fn : mn;
      am[(size_t)bn * C2 + c2] = __floats2half2_rn(fx, fn);  // (max, min)
    }
    __syncthreads();
  }
  dred[t] = accs; __syncthreads();
  if (g == 0) part[(size_t)blockIdx.x * 256 + t] = dred[t] + dred[t + 128];
  __syncthreads();
  dred[t] = accq; __syncthreads();
  if (g == 0) part[(size_t)blockIdx.x * 256 + 128 + t] = dred[t] + dred[t + 128];
}

// ---------------- BN2 finalize: reduce per-block partials, one block per channel ----------------
__global__ __launch_bounds__(256) void finalize2_kernel(const double* __restrict__ part,
                                 const float* __restrict__ g2w, const float* __restrict__ be2,
                                 float* __restrict__ scale2, float* __restrict__ shift2) {
  int c = blockIdx.x;   // 128
  int t = threadIdx.x;  // 256
  double s = 0, q = 0;
  for (int i = t; i < EDGE2_GRID; i += 256) {
    s += part[(size_t)i * 256 + c];
    q += part[(size_t)i * 256 + 128 + c];
  }
  __shared__ double shs[256], shq[256];
  shs[t] = s; shq[t] = q; __syncthreads();
  for (int off = 128; off > 0; off >>= 1) {
    if (t < off) { shs[t] += shs[t + off]; shq[t] += shq[t + off]; }
    __syncthreads();
  }
  if (t == 0) {
    double mean = shs[0] / R1d;
    double var = shq[0] / R1d - mean * mean;
    double sc = (double)g2w[c] / sqrt(var + 1e-5);
    scale2[c] = (float)sc;
    shift2[c] = (float)((double)be2[c] - mean * sc);
  }
}

// node value on the fly: relu(scale * (scale>=0 ? max : min) + shift)
static __device__ __forceinline__ float node_val(__half2 h2, float s, float sh) {
  float A = __low2float(h2), N = __high2float(h2);
  float v = (s >= 0.f ? A : N) * s + sh;
  return v > 0.f ? v : 0.f;
}

// ---------------- Gram partials: BN2 applied on the fly; private 128x128 partial + colsum ----------------
__global__ __launch_bounds__(256) void gram_part_kernel(const __half2* __restrict__ am,
                                                        const float* __restrict__ scale2, const float* __restrict__ shift2,
                                                        float* __restrict__ part) {
  __shared__ float tile[64 * C2];  // 32 KiB
  __shared__ float s_s[C2], s_h[C2];
  int t = threadIdx.x;
  if (t < C2) { s_s[t] = scale2[t]; s_h[t] = shift2[t]; }
  __syncthreads();
  int i = t & 127, jh = t >> 7;
  float acc[64];
  #pragma unroll
  for (int u = 0; u < 64; ++u) acc[u] = 0.f;
  float csum = 0.f;
  for (int tl = blockIdx.x; tl < NNODE / 64; tl += GRAM_GRID) {
    const __half2* a2 = am + (size_t)tl * 64 * C2;
    #pragma unroll
    for (int q = 0; q < 32; ++q) {
      int e = q * 256 + t;
      int c = e & 127;
      tile[e] = node_val(a2[e], s_s[c], s_h[c]);
    }
    __syncthreads();
    #pragma unroll 4
    for (int r = 0; r < 64; ++r) {
      float xi = tile[r * C2 + i];
      const float4* row4 = (const float4*)&tile[r * C2 + jh * 64];
      #pragma unroll
      for (int u4 = 0; u4 < 16; ++u4) {
        float4 v = row4[u4];
        acc[u4 * 4 + 0] += xi * v.x;
        acc[u4 * 4 + 1] += xi * v.y;
        acc[u4 * 4 + 2] += xi * v.z;
        acc[u4 * 4 + 3] += xi * v.w;
      }
    }
    if (t < 128) {
      #pragma unroll 8
      for (int r = 0; r < 64; ++r) csum += tile[r * C2 + t];
    }
    __syncthreads();
  }
  float* pb = part + (size_t)blockIdx.x * GRAM_ELEMS;
  float4* pout = (float4*)(pb + (size_t)i * C2 + jh * 64);
  #pragma unroll
  for (int u4 = 0; u4 < 16; ++u4)
    pout[u4] = make_float4(acc[u4 * 4], acc[u4 * 4 + 1], acc[u4 * 4 + 2], acc[u4 * 4 + 3]);
  if (t < 128) pb[C2 * C2 + t] = csum;
}

// ---------------- Gram reduce: sum partials -> f64 G2 + nodesum ----------------
__global__ __launch_bounds__(256) void gram_reduce_kernel(const float* __restrict__ part,
                                                          double* __restrict__ G2, double* __restrict__ nodesum) {
  int e = blockIdx.x * 256 + threadIdx.x;
  if (e >= GRAM_ELEMS) return;
  double s = 0;
  for (int p = 0; p < GRAM_GRID; ++p) s += (double)part[(size_t)p * GRAM_ELEMS + e];
  if (e < C2 * C2) G2[e] = s;
  else nodesum[e - C2 * C2] = s;
}

// ---------------- BN3 coeffs from Gram ----------------
__global__ __launch_bounds__(128) void finalize3_kernel(const double* __restrict__ G2, const double* __restrict__ nodesum,
    const float* __restrict__ W3, const float* __restrict__ b3,
    const float* __restrict__ g3, const float* __restrict__ be3,
    float* __restrict__ scale3, float* __restrict__ shift3) {
  int c = blockIdx.x;   // 1024 channels
  int t = threadIdx.x;  // 128
  __shared__ double wsh[128];
  __shared__ double sh[128];
  double w = W3[(size_t)t * EMB + c];
  wsh[t] = w;
  __syncthreads();
  double rowdot = 0;
  for (int j = 0; j < 128; ++j) rowdot += G2[(size_t)j * C2 + t] * wsh[j];
  sh[t] = w * rowdot;
  __syncthreads();
  for (int off = 64; off > 0; off >>= 1) { if (t < off) sh[t] += sh[t + off]; __syncthreads(); }
  double quad = sh[0];
  __syncthreads();
  sh[t] = w * nodesum[t];
  __syncthreads();
  for (int off = 64; off > 0; off >>= 1) { if (t < off) sh[t] += sh[t + off]; __syncthreads(); }
  if (t == 0) {
    double wm = sh[0];
    double bb = b3[c];
    double mean = wm / R3d + bb;
    double E2 = (quad + 2.0 * bb * wm) / R3d + bb * bb;
    double var = E2 - mean * mean;
    double sc = (double)g3[c] / sqrt(var + 1e-5);
    scale3[c] = (float)sc;
    shift3[c] = (float)((double)be3[c] - mean * sc);
  }
}

// ---------------- linear1 apply (BN2 on the fly) + BN3 + ReLU -> per-row-tile partial max/sum ----------------
__global__ __launch_bounds__(256) void apply3pool_kernel(const __half2* __restrict__ am,
    const float* __restrict__ scale2, const float* __restrict__ shift2,
    const float* __restrict__ W3, const float* __restrict__ b3,
    const float* __restrict__ scale3, const float* __restrict__ shift3,
    float* __restrict__ pp, float* __restrict__ ps) {
  __shared__ float tile[32 * C2];  // 16 KiB
  __shared__ float s_s[C2], s_h[C2];
  int rt = blockIdx.x;  // 1024 row tiles of 32 rows
  int ct = blockIdx.y;  // 2 column halves
  int t = threadIdx.x;
  if (t < C2) { s_s[t] = scale2[t]; s_h[t] = shift2[t]; }
  __syncthreads();
  int c0 = ct * 512 + t;
  int c1 = c0 + 256;
  const __half2* a2 = am + (size_t)rt * 32 * C2;
  #pragma unroll
  for (int q = 0; q < 16; ++q) {
    int e = q * 256 + t;
    int c = e & 127;
    tile[e] = node_val(a2[e], s_s[c], s_h[c]);
  }
  __syncthreads();
  float a0[32], a1[32];
  #pragma unroll
  for (int r = 0; r < 32; ++r) { a0[r] = 0.f; a1[r] = 0.f; }
  for (int j = 0; j < 128; j += 4) {
    float w00 = W3[(size_t)j * EMB + c0], w01 = W3[(size_t)(j + 1) * EMB + c0];
    float w02 = W3[(size_t)(j + 2) * EMB + c0], w03 = W3[(size_t)(j + 3) * EMB + c0];
    float w10 = W3[(size_t)j * EMB + c1], w11 = W3[(size_t)(j + 1) * EMB + c1];
    float w12 = W3[(size_t)(j + 2) * EMB + c1], w13 = W3[(size_t)(j + 3) * EMB + c1];
    #pragma unroll
    for (int r = 0; r < 32; ++r) {
      float4 v = *(const float4*)&tile[r * C2 + j];
      a0[r] += v.x * w00 + v.y * w01 + v.z * w02 + v.w * w03;
      a1[r] += v.x * w10 + v.y * w11 + v.z * w12 + v.w * w13;
    }
  }
  float b30 = b3[c0], s30 = scale3[c0], sh30 = shift3[c0];
  float b31 = b3[c1], s31 = scale3[c1], sh31 = shift3[c1];
  float mx0 = 0.f, sm0 = 0.f, mx1 = 0.f, sm1 = 0.f;
  #pragma unroll
  for (int r = 0; r < 32; ++r) {
    float x0 = (a0[r] + b30) * s30 + sh30; x0 = x0 > 0.f ? x0 : 0.f; mx0 = mx0 > x0 ? mx0 : x0; sm0 += x0;
    float x1 = (a1[r] + b31) * s31 + sh31; x1 = x1 > 0.f ? x1 : 0.f; mx1 = mx1 > x1 ? mx1 : x1; sm1 += x1;
  }
  float* ppb = pp + (size_t)rt * EMB;
  float* psb = ps + (size_t)rt * EMB;
  ppb[c0] = mx0; psb[c0] = sm0;
  ppb[c1] = mx1; psb[c1] = sm1;
}

// ---------------- pool reduce: per (b,c) max/sum over 64 row tiles ----------------
__global__ __launch_bounds__(256) void poolreduce_kernel(const float* __restrict__ pp, const float* __restrict__ ps,
                                                         float* __restrict__ pmaxo, float* __restrict__ psumo) {
  int e = blockIdx.x * 256 + threadIdx.x;  // e = b*1024 + c, grid 64
  int b = e >> 10, c = e & 1023;
  const float* bp = pp + ((size_t)b * 64) * EMB + c;
  const float* bs = ps + ((size_t)b * 64) * EMB + c;
  float mx = 0.f, sm = 0.f;
  #pragma unroll 8
  for (int tl = 0; tl < 64; ++tl) {
    float v = bp[(size_t)tl * EMB];
    float s = bs[(size_t)tl * EMB];
    mx = mx > v ? mx : v;
    sm += s;
  }
  pmaxo[e] = mx;
  psumo[e] = sm;
}

// ---------------- final linear: pooled[16,2048] @ W4 + b4 -> out[16,7] ----------------
__global__ __launch_bounds__(64) void final_kernel(const float* __restrict__ pmax, const float* __restrict__ psum,
    const float* __restrict__ W4, const float* __restrict__ b4, float* __restrict__ out) {
  int b = blockIdx.x, t = threadIdx.x;
  #pragma unroll
  for (int o = 0; o < OUT; ++o) {
    float acc = 0.f;
    for (int tt = t; tt < 2 * EMB; tt += 64) {
      float p = (tt < EMB) ? pmax[(size_t)b * EMB + tt]
                           : psum[(size_t)b * EMB + tt - EMB] * (1.0f / (float)NPT);
      acc += p * W4[(size_t)tt * OUT + o];
    }
    #pragma unroll
    for (int off = 32; off > 0; off >>= 1) acc += __shfl_down(acc, off);
    if (t == 0) out[b * OUT + o] = acc + b4[o];
  }
}

extern "C" void kernel_launch(void* const* d_in, const int* in_sizes, int n_in,
                              void* d_out, int out_size, void* d_ws, size_t ws_size,
                              hipStream_t stream) {
  const float* pos = (const float*)d_in[0];
  const float* W1 = (const float*)d_in[1];  const float* b1 = (const float*)d_in[2];
  const float* g1 = (const float*)d_in[3];  const float* be1 = (const float*)d_in[4];
  const float* W2 = (const float*)d_in[5];  const float* b2 = (const float*)d_in[6];
  const float* g2 = (const float*)d_in[7];  const float* be2 = (const float*)d_in[8];
  const float* W3 = (const float*)d_in[9];  const float* b3 = (const float*)d_in[10];
  const float* g3 = (const float*)d_in[11]; const float* be3 = (const float*)d_in[12];
  const float* W4 = (const float*)d_in[13]; const float* b4 = (const float*)d_in[14];
  float* out = (float*)d_out;

  // ---- workspace layout, total ~25.6 MiB (round-2's 35 MiB layout was proven safe) ----
  char* ws = (char*)d_ws;
  unsigned short* idx = (unsigned short*)ws;               // NEDGE u16 = 1.25 MiB
  __half2* am = (__half2*)(ws + (size_t)NEDGE * 2);        // NNODE*C2 half2 = 16 MiB
  char* smallbase = (char*)(am + (size_t)NNODE * C2);

  double* dstats  = (double*)smallbase;           // 32 (27 used)
  double* G2      = dstats + 32;                  // 16384
  double* nodesum = G2 + 16384;                   // 128
  float* scale1 = (float*)(nodesum + 128);
  float* shift1 = scale1 + C1;
  float* scale2 = shift1 + C1;
  float* shift2 = scale2 + C2;
  float* scale3 = shift2 + C2;
  float* shift3 = scale3 + EMB;
  float* pooledmax = shift3 + EMB;                // 16*1024
  float* pooledsum = pooledmax + NB * EMB;        // 16*1024
  char* scratch = (char*)(pooledsum + NB * EMB);
  // lifetime-disjoint overlays on one ~8.45 MiB slab:
  double* eg_part  = (double*)scratch;            // 4096*256*8  = 8.00 MiB (edge2 -> finalize2)
  float* gram_part = (float*)scratch;             // 128*16512*4 = 8.06 MiB (gram_part -> gram_reduce)
  float* pp        = (float*)scratch;             // 1024*1024*4 = 4 MiB    (apply3pool -> poolreduce)
  float* psb       = pp + (size_t)1024 * EMB;     // 4 MiB

  hipMemsetAsync(dstats, 0, 32 * sizeof(double), stream);

  knn_kernel<<<NB * NPT / 4, 256, 0, stream>>>(pos, idx);
  statse_kernel<<<512, 256, 0, stream>>>(pos, idx, dstats);
  finalize1_kernel<<<1, 64, 0, stream>>>(dstats, W1, b1, g1, be1, scale1, shift1);
  edge2_kernel<<<EDGE2_GRID, 256, 0, stream>>>(pos, idx, W1, b1, scale1, shift1, W2, b2, am, eg_part);
  finalize2_kernel<<<C2, 256, 0, stream>>>(eg_part, g2, be2, scale2, shift2);
  gram_part_kernel<<<GRAM_GRID, 256, 0, stream>>>(am, scale2, shift2, gram_part);
  gram_reduce_kernel<<<(GRAM_ELEMS + 255) / 256, 256, 0, stream>>>(gram_part, G2, nodesum);
  finalize3_kernel<<<EMB, 128, 0, stream>>>(G2, nodesum, W3, b3, g3, be3, scale3, shift3);
  apply3pool_kernel<<<dim3(1024, 2), 256, 0, stream>>>(am, scale2, shift2, W3, b3, scale3, shift3, pp, psb);
  poolreduce_kernel<<<NB * EMB / 256, 256, 0, stream>>>(pp, psb, pooledmax, pooledsum);
  final_kernel<<<NB, 64, 0, stream>>>(pooledmax, pooledsum, W4, b4, out);
}

// Round 5
// 807.575 us; speedup vs baseline: 2.1350x; 1.0206x over previous
//
#include <hip/hip_runtime.h>
#include <hip/hip_fp16.h>
#include <float.h>

// ---- fixed problem shape ----
constexpr int NB  = 16;     // batch (clouds)
constexpr int NPT = 2048;   // points per cloud
constexpr int KK  = 20;     // kNN
constexpr int NEDGE = NB * NPT * KK;       // 655360
constexpr int C1 = 64, C2 = 128, EMB = 1024, OUT = 7;
constexpr int NNODE = NB * NPT;            // 32768
constexpr int EDGE2_GRID = 4096;
constexpr int GRAM_GRID = 128;
constexpr int GRAM_ELEMS = C2 * C2 + C2;   // 16512 (Gram + colsum)
__device__ constexpr double R1d = (double)NEDGE;       // BN1/BN2 row count
__device__ constexpr double R3d = (double)(NB * NPT);  // BN3 row count
constexpr unsigned long long INF64 = ~0ull;

// ---------------- kNN: one wave per query, keys fully register-resident ----------------
// key[] must be indexed ONLY by compile-time constants (full unroll) or the
// array lands in scratch (round-4 profile: 525 MB spill writes, 278 us).
__global__ __launch_bounds__(256) void knn_kernel(const float* __restrict__ pos, unsigned short* __restrict__ idxo) {
  int t = threadIdx.x;
  int lane = t & 63, w = t >> 6;
  int bn = blockIdx.x * 4 + w;            // 8192 blocks x 4 waves = 32768 queries
  int b = bn >> 11, n = bn & (NPT - 1);
  const float* pb = pos + (size_t)b * NPT * 3;
  float xn = pb[n * 3], yn = pb[n * 3 + 1], zn = pb[n * 3 + 2];
  float sqn = xn * xn + yn * yn + zn * zn;

  unsigned long long key[32];
  #pragma unroll
  for (int i = 0; i < 32; ++i) {
    int m = i * 64 + lane;
    float xm = pb[m * 3], ym = pb[m * 3 + 1], zm = pb[m * 3 + 2];
    float sqm = xm * xm + ym * ym + zm * zm;
    float dt = xn * xm + yn * ym + zn * zm;
    float d = sqn + sqm - 2.0f * dt;
    unsigned ub = __float_as_uint(d);
    ub = (ub & 0x80000000u) ? ~ub : (ub | 0x80000000u);  // order-preserving map
    key[i] = ((unsigned long long)ub << 32) | (unsigned long long)(unsigned)m;
  }

  unsigned long long T = 0;
  int myidx = 0;
  for (int r = 0; r < KK; ++r) {
    unsigned long long t0[16];
    #pragma unroll
    for (int i = 0; i < 16; ++i) {
      unsigned long long a = key[2 * i]     >= T ? key[2 * i]     : INF64;
      unsigned long long c = key[2 * i + 1] >= T ? key[2 * i + 1] : INF64;
      t0[i] = a < c ? a : c;
    }
    #pragma unroll
    for (int s = 8; s > 0; s >>= 1)
      #pragma unroll
      for (int i = 0; i < 8; ++i)
        if (i < s) t0[i] = t0[i] < t0[i + s] ? t0[i] : t0[i + s];
    unsigned long long best = t0[0];
    #pragma unroll
    for (int off = 32; off > 0; off >>= 1) {
      unsigned long long o = (unsigned long long)__shfl_xor((long long)best, off, 64);
      best = best < o ? best : o;
    }
    if (lane == r) myidx = (int)(unsigned)(best & 0xffffffffull);
    T = best + 1;
  }
  if (lane < KK) idxo[(size_t)bn * KK + lane] = (unsigned short)myidx;
}

// ---------------- edge-feature first/second moments (6 + 21 doubles) ----------------
__global__ __launch_bounds__(256) void statse_kernel(const float* __restrict__ pos, const unsigned short* __restrict__ idx,
                                                     double* __restrict__ dstats) {
  float acc[27];
  #pragma unroll
  for (int i = 0; i < 27; ++i) acc[i] = 0.f;
  int t = threadIdx.x;
  for (int e = blockIdx.x * 256 + t; e < NEDGE; e += gridDim.x * 256) {
    int bn = e / KK;
    int b = bn >> 11, n = bn & (NPT - 1);
    int j = idx[e];
    const float* pb = pos + (size_t)b * NPT * 3;
    float f[6];
    f[0] = pb[n * 3]; f[1] = pb[n * 3 + 1]; f[2] = pb[n * 3 + 2];
    f[3] = pb[j * 3] - f[0]; f[4] = pb[j * 3 + 1] - f[1]; f[5] = pb[j * 3 + 2] - f[2];
    int p = 6;
    #pragma unroll
    for (int d = 0; d < 6; ++d) acc[d] += f[d];
    #pragma unroll
    for (int d = 0; d < 6; ++d)
      #pragma unroll
      for (int q = d; q < 6; ++q) { acc[p] += f[d] * f[q]; ++p; }
  }
  __shared__ float sred[4][27];
  int lane = t & 63, w = t >> 6;
  #pragma unroll
  for (int c = 0; c < 27; ++c) {
    float v = acc[c];
    #pragma unroll
    for (int off = 32; off > 0; off >>= 1) v += __shfl_down(v, off);
    if (lane == 0) sred[w][c] = v;
  }
  __syncthreads();
  if (t < 27) {
    double s = (double)sred[0][t] + (double)sred[1][t] + (double)sred[2][t] + (double)sred[3][t];
    atomicAdd(&dstats[t], s);
  }
}

// ---------------- BN1 coeffs from moments ----------------
__global__ void finalize1_kernel(const double* __restrict__ dstats, const float* __restrict__ W1,
                                 const float* __restrict__ b1, const float* __restrict__ g1,
                                 const float* __restrict__ be1, float* __restrict__ scale1,
                                 float* __restrict__ shift1) {
  int c = threadIdx.x;  // 64
  double m1[6], M2[6][6];
  for (int d = 0; d < 6; ++d) m1[d] = dstats[d];
  int p = 6;
  for (int d = 0; d < 6; ++d)
    for (int q = d; q < 6; ++q) { M2[d][q] = dstats[p]; M2[q][d] = dstats[p]; ++p; }
  double w[6];
  for (int d = 0; d < 6; ++d) w[d] = W1[d * C1 + c];
  double wm = 0, quad = 0;
  for (int d = 0; d < 6; ++d) wm += w[d] * m1[d];
  for (int d = 0; d < 6; ++d) {
    double s = 0;
    for (int q = 0; q < 6; ++q) s += M2[d][q] * w[q];
    quad += w[d] * s;
  }
  double bb = b1[c];
  double mean = wm / R1d + bb;
  double E2 = (quad + 2.0 * bb * wm) / R1d + bb * bb;
  double var = E2 - mean * mean;
  double sc = (double)g1[c] / sqrt(var + 1e-5);
  scale1[c] = (float)sc;
  shift1[c] = (float)((double)be1[c] - mean * sc);
}

// ---------------- fused edge pass: BN2 partial stats + per-node (max,min) of a2 as half2 ----------------
__global__ __launch_bounds__(256) void edge2_kernel(const float* __restrict__ pos, const unsigned short* __restrict__ idx,
    const float* __restrict__ W1, const float* __restrict__ b1,
    const float* __restrict__ scale1, const float* __restrict__ shift1,
    const float* __restrict__ W2, const float* __restrict__ b2,
    __half2* __restrict__ am, double* __restrict__ part) {
  __shared__ float e_lds[KK * 6];
  __shared__ float h_lds[KK * C1];
  __shared__ float redmx[128];
  __shared__ float redmn[128];
  __shared__ double dred[256];
  int t = threadIdx.x;
  int c2 = t & 127, g = t >> 7;
  float w2c[C1];
  #pragma unroll
  for (int j = 0; j < C1; ++j) w2c[j] = W2[j * C2 + c2];
  float b2c = b2[c2];
  double accs = 0.0, accq = 0.0;
  for (int bn = blockIdx.x; bn < NB * NPT; bn += gridDim.x) {
    if (t < KK * 6) {
      int r = t / 6, comp = t - (t / 6) * 6;
      int e = bn * KK + r;
      int b = bn >> 11, n = bn & (NPT - 1);
      int j = idx[e];
      const float* pb = pos + (size_t)b * NPT * 3;
      float v;
      if (comp < 3) v = pb[n * 3 + comp];
      else          v = pb[j * 3 + comp - 3] - pb[n * 3 + comp - 3];
      e_lds[r * 6 + comp] = v;
    }
    __syncthreads();
    #pragma unroll
    for (int i = 0; i < 5; ++i) {
      int slot = t + 256 * i;
      int r = slot >> 6, c1 = slot & 63;
      float a = b1[c1];
      #pragma unroll
      for (int d = 0; d < 6; ++d) a += e_lds[r * 6 + d] * W1[d * C1 + c1];
      a = a * scale1[c1] + shift1[c1];
      h_lds[slot] = a > 0.f ? a : 0.f;
    }
    __syncthreads();
    float mx = -FLT_MAX, mn = FLT_MAX;
    #pragma unroll
    for (int rr = 0; rr < 10; ++rr) {
      int r = g * 10 + rr;
      float a = b2c;
      #pragma unroll
      for (int j = 0; j < C1; ++j) a += h_lds[r * C1 + j] * w2c[j];
      accs += (double)a;
      accq += (double)a * (double)a;
      mx = mx > a ? mx : a;
      mn = mn < a ? mn : a;
    }
    if (g == 0) { redmx[c2] = mx; redmn[c2] = mn; }
    __syncthreads();
    if (g == 1) {
      float fx = redmx[c2], fn = redmn[c2];
      fx = fx > mx ? fx : mx;
      fn = fn < mn ? fn : mn;
      am[(size_t)bn * C2 + c2] = __floats2half2_rn(fx, fn);  // (max, min)
    }
    __syncthreads();
  }
  dred[t] = accs; __syncthreads();
  if (g == 0) part[(size_t)blockIdx.x * 256 + t] = dred[t] + dred[t + 128];
  __syncthreads();
  dred[t] = accq; __syncthreads();
  if (g == 0) part[(size_t)blockIdx.x * 256 + 128 + t] = dred[t] + dred[t + 128];
}

// ---------------- BN2 finalize: reduce per-block partials, one block per channel ----------------
__global__ __launch_bounds__(256) void finalize2_kernel(const double* __restrict__ part,
                                 const float* __restrict__ g2w, const float* __restrict__ be2,
                                 float* __restrict__ scale2, float* __restrict__ shift2) {
  int c = blockIdx.x;   // 128
  int t = threadIdx.x;  // 256
  double s = 0, q = 0;
  for (int i = t; i < EDGE2_GRID; i += 256) {
    s += part[(size_t)i * 256 + c];
    q += part[(size_t)i * 256 + 128 + c];
  }
  __shared__ double shs[256], shq[256];
  shs[t] = s; shq[t] = q; __syncthreads();
  for (int off = 128; off > 0; off >>= 1) {
    if (t < off) { shs[t] += shs[t + off]; shq[t] += shq[t + off]; }
    __syncthreads();
  }
  if (t == 0) {
    double mean = shs[0] / R1d;
    double var = shq[0] / R1d - mean * mean;
    double sc = (double)g2w[c] / sqrt(var + 1e-5);
    scale2[c] = (float)sc;
    shift2[c] = (float)((double)be2[c] - mean * sc);
  }
}

// node value on the fly: relu(scale * (scale>=0 ? max : min) + shift)
static __device__ __forceinline__ float node_val(__half2 h2, float s, float sh) {
  float A = __low2float(h2), N = __high2float(h2);
  float v = (s >= 0.f ? A : N) * s + sh;
  return v > 0.f ? v : 0.f;
}

// ---------------- Gram partials: BN2 applied on the fly; private 128x128 partial + colsum ----------------
__global__ __launch_bounds__(256) void gram_part_kernel(const __half2* __restrict__ am,
                                                        const float* __restrict__ scale2, const float* __restrict__ shift2,
                                                        float* __restrict__ part) {
  __shared__ float tile[64 * C2];  // 32 KiB
  __shared__ float s_s[C2], s_h[C2];
  int t = threadIdx.x;
  if (t < C2) { s_s[t] = scale2[t]; s_h[t] = shift2[t]; }
  __syncthreads();
  int i = t & 127, jh = t >> 7;
  float acc[64];
  #pragma unroll
  for (int u = 0; u < 64; ++u) acc[u] = 0.f;
  float csum = 0.f;
  for (int tl = blockIdx.x; tl < NNODE / 64; tl += GRAM_GRID) {
    const __half2* a2 = am + (size_t)tl * 64 * C2;
    #pragma unroll
    for (int q = 0; q < 32; ++q) {
      int e = q * 256 + t;
      int c = e & 127;
      tile[e] = node_val(a2[e], s_s[c], s_h[c]);
    }
    __syncthreads();
    #pragma unroll 4
    for (int r = 0; r < 64; ++r) {
      float xi = tile[r * C2 + i];
      const float4* row4 = (const float4*)&tile[r * C2 + jh * 64];
      #pragma unroll
      for (int u4 = 0; u4 < 16; ++u4) {
        float4 v = row4[u4];
        acc[u4 * 4 + 0] += xi * v.x;
        acc[u4 * 4 + 1] += xi * v.y;
        acc[u4 * 4 + 2] += xi * v.z;
        acc[u4 * 4 + 3] += xi * v.w;
      }
    }
    if (t < 128) {
      #pragma unroll 8
      for (int r = 0; r < 64; ++r) csum += tile[r * C2 + t];
    }
    __syncthreads();
  }
  float* pb = part + (size_t)blockIdx.x * GRAM_ELEMS;
  float4* pout = (float4*)(pb + (size_t)i * C2 + jh * 64);
  #pragma unroll
  for (int u4 = 0; u4 < 16; ++u4)
    pout[u4] = make_float4(acc[u4 * 4], acc[u4 * 4 + 1], acc[u4 * 4 + 2], acc[u4 * 4 + 3]);
  if (t < 128) pb[C2 * C2 + t] = csum;
}

// ---------------- Gram reduce: sum partials -> f64 G2 + nodesum ----------------
__global__ __launch_bounds__(256) void gram_reduce_kernel(const float* __restrict__ part,
                                                          double* __restrict__ G2, double* __restrict__ nodesum) {
  int e = blockIdx.x * 256 + threadIdx.x;
  if (e >= GRAM_ELEMS) return;
  double s = 0;
  for (int p = 0; p < GRAM_GRID; ++p) s += (double)part[(size_t)p * GRAM_ELEMS + e];
  if (e < C2 * C2) G2[e] = s;
  else nodesum[e - C2 * C2] = s;
}

// ---------------- BN3 coeffs from Gram ----------------
__global__ __launch_bounds__(128) void finalize3_kernel(const double* __restrict__ G2, const double* __restrict__ nodesum,
    const float* __restrict__ W3, const float* __restrict__ b3,
    const float* __restrict__ g3, const float* __restrict__ be3,
    float* __restrict__ scale3, float* __restrict__ shift3) {
  int c = blockIdx.x;   // 1024 channels
  int t = threadIdx.x;  // 128
  __shared__ double wsh[128];
  __shared__ double sh[128];
  double w = W3[(size_t)t * EMB + c];
  wsh[t] = w;
  __syncthreads();
  double rowdot = 0;
  for (int j = 0; j < 128; ++j) rowdot += G2[(size_t)j * C2 + t] * wsh[j];
  sh[t] = w * rowdot;
  __syncthreads();
  for (int off = 64; off > 0; off >>= 1) { if (t < off) sh[t] += sh[t + off]; __syncthreads(); }
  double quad = sh[0];
  __syncthreads();
  sh[t] = w * nodesum[t];
  __syncthreads();
  for (int off = 64; off > 0; off >>= 1) { if (t < off) sh[t] += sh[t + off]; __syncthreads(); }
  if (t == 0) {
    double wm = sh[0];
    double bb = b3[c];
    double mean = wm / R3d + bb;
    double E2 = (quad + 2.0 * bb * wm) / R3d + bb * bb;
    double var = E2 - mean * mean;
    double sc = (double)g3[c] / sqrt(var + 1e-5);
    scale3[c] = (float)sc;
    shift3[c] = (float)((double)be3[c] - mean * sc);
  }
}

// ---------------- linear1 apply (BN2 on the fly) + BN3 + ReLU -> per-row-tile partial max/sum ----------------
__global__ __launch_bounds__(256) void apply3pool_kernel(const __half2* __restrict__ am,
    const float* __restrict__ scale2, const float* __restrict__ shift2,
    const float* __restrict__ W3, const float* __restrict__ b3,
    const float* __restrict__ scale3, const float* __restrict__ shift3,
    float* __restrict__ pp, float* __restrict__ ps) {
  __shared__ float tile[32 * C2];  // 16 KiB
  __shared__ float s_s[C2], s_h[C2];
  int rt = blockIdx.x;  // 1024 row tiles of 32 rows
  int ct = blockIdx.y;  // 2 column halves
  int t = threadIdx.x;
  if (t < C2) { s_s[t] = scale2[t]; s_h[t] = shift2[t]; }
  __syncthreads();
  int c0 = ct * 512 + t;
  int c1 = c0 + 256;
  const __half2* a2 = am + (size_t)rt * 32 * C2;
  #pragma unroll
  for (int q = 0; q < 16; ++q) {
    int e = q * 256 + t;
    int c = e & 127;
    tile[e] = node_val(a2[e], s_s[c], s_h[c]);
  }
  __syncthreads();
  float a0[32], a1[32];
  #pragma unroll
  for (int r = 0; r < 32; ++r) { a0[r] = 0.f; a1[r] = 0.f; }
  for (int j = 0; j < 128; j += 4) {
    float w00 = W3[(size_t)j * EMB + c0], w01 = W3[(size_t)(j + 1) * EMB + c0];
    float w02 = W3[(size_t)(j + 2) * EMB + c0], w03 = W3[(size_t)(j + 3) * EMB + c0];
    float w10 = W3[(size_t)j * EMB + c1], w11 = W3[(size_t)(j + 1) * EMB + c1];
    float w12 = W3[(size_t)(j + 2) * EMB + c1], w13 = W3[(size_t)(j + 3) * EMB + c1];
    #pragma unroll
    for (int r = 0; r < 32; ++r) {
      float4 v = *(const float4*)&tile[r * C2 + j];
      a0[r] += v.x * w00 + v.y * w01 + v.z * w02 + v.w * w03;
      a1[r] += v.x * w10 + v.y * w11 + v.z * w12 + v.w * w13;
    }
  }
  float b30 = b3[c0], s30 = scale3[c0], sh30 = shift3[c0];
  float b31 = b3[c1], s31 = scale3[c1], sh31 = shift3[c1];
  float mx0 = 0.f, sm0 = 0.f, mx1 = 0.f, sm1 = 0.f;
  #pragma unroll
  for (int r = 0; r < 32; ++r) {
    float x0 = (a0[r] + b30) * s30 + sh30; x0 = x0 > 0.f ? x0 : 0.f; mx0 = mx0 > x0 ? mx0 : x0; sm0 += x0;
    float x1 = (a1[r] + b31) * s31 + sh31; x1 = x1 > 0.f ? x1 : 0.f; mx1 = mx1 > x1 ? mx1 : x1; sm1 += x1;
  }
  float* ppb = pp + (size_t)rt * EMB;
  float* psb = ps + (size_t)rt * EMB;
  ppb[c0] = mx0; psb[c0] = sm0;
  ppb[c1] = mx1; psb[c1] = sm1;
}

// ---------------- pool reduce: per (b,c) max/sum over 64 row tiles ----------------
__global__ __launch_bounds__(256) void poolreduce_kernel(const float* __restrict__ pp, const float* __restrict__ ps,
                                                         float* __restrict__ pmaxo, float* __restrict__ psumo) {
  int e = blockIdx.x * 256 + threadIdx.x;  // e = b*1024 + c, grid 64
  int b = e >> 10, c = e & 1023;
  const float* bp = pp + ((size_t)b * 64) * EMB + c;
  const float* bs = ps + ((size_t)b * 64) * EMB + c;
  float mx = 0.f, sm = 0.f;
  #pragma unroll 8
  for (int tl = 0; tl < 64; ++tl) {
    float v = bp[(size_t)tl * EMB];
    float s = bs[(size_t)tl * EMB];
    mx = mx > v ? mx : v;
    sm += s;
  }
  pmaxo[e] = mx;
  psumo[e] = sm;
}

// ---------------- final linear: pooled[16,2048] @ W4 + b4 -> out[16,7] ----------------
__global__ __launch_bounds__(64) void final_kernel(const float* __restrict__ pmax, const float* __restrict__ psum,
    const float* __restrict__ W4, const float* __restrict__ b4, float* __restrict__ out) {
  int b = blockIdx.x, t = threadIdx.x;
  #pragma unroll
  for (int o = 0; o < OUT; ++o) {
    float acc = 0.f;
    for (int tt = t; tt < 2 * EMB; tt += 64) {
      float p = (tt < EMB) ? pmax[(size_t)b * EMB + tt]
                           : psum[(size_t)b * EMB + tt - EMB] * (1.0f / (float)NPT);
      acc += p * W4[(size_t)tt * OUT + o];
    }
    #pragma unroll
    for (int off = 32; off > 0; off >>= 1) acc += __shfl_down(acc, off);
    if (t == 0) out[b * OUT + o] = acc + b4[o];
  }
}

extern "C" void kernel_launch(void* const* d_in, const int* in_sizes, int n_in,
                              void* d_out, int out_size, void* d_ws, size_t ws_size,
                              hipStream_t stream) {
  const float* pos = (const float*)d_in[0];
  const float* W1 = (const float*)d_in[1];  const float* b1 = (const float*)d_in[2];
  const float* g1 = (const float*)d_in[3];  const float* be1 = (const float*)d_in[4];
  const float* W2 = (const float*)d_in[5];  const float* b2 = (const float*)d_in[6];
  const float* g2 = (const float*)d_in[7];  const float* be2 = (const float*)d_in[8];
  const float* W3 = (const float*)d_in[9];  const float* b3 = (const float*)d_in[10];
  const float* g3 = (const float*)d_in[11]; const float* be3 = (const float*)d_in[12];
  const float* W4 = (const float*)d_in[13]; const float* b4 = (const float*)d_in[14];
  float* out = (float*)d_out;

  // ---- workspace layout, total ~25.6 MiB (proven safe at 25.6 MiB in round 4) ----
  char* ws = (char*)d_ws;
  unsigned short* idx = (unsigned short*)ws;               // NEDGE u16 = 1.25 MiB
  __half2* am = (__half2*)(ws + (size_t)NEDGE * 2);        // NNODE*C2 half2 = 16 MiB
  char* smallbase = (char*)(am + (size_t)NNODE * C2);

  double* dstats  = (double*)smallbase;           // 32 (27 used)
  double* G2      = dstats + 32;                  // 16384
  double* nodesum = G2 + 16384;                   // 128
  float* scale1 = (float*)(nodesum + 128);
  float* shift1 = scale1 + C1;
  float* scale2 = shift1 + C1;
  float* shift2 = scale2 + C2;
  float* scale3 = shift2 + C2;
  float* shift3 = scale3 + EMB;
  float* pooledmax = shift3 + EMB;                // 16*1024
  float* pooledsum = pooledmax + NB * EMB;        // 16*1024
  char* scratch = (char*)(pooledsum + NB * EMB);
  // lifetime-disjoint overlays on one ~8.45 MiB slab:
  double* eg_part  = (double*)scratch;            // 4096*256*8  = 8.00 MiB (edge2 -> finalize2)
  float* gram_part = (float*)scratch;             // 128*16512*4 = 8.06 MiB (gram_part -> gram_reduce)
  float* pp        = (float*)scratch;             // 1024*1024*4 = 4 MiB    (apply3pool -> poolreduce)
  float* psb       = pp + (size_t)1024 * EMB;     // 4 MiB

  hipMemsetAsync(dstats, 0, 32 * sizeof(double), stream);

  knn_kernel<<<NB * NPT / 4, 256, 0, stream>>>(pos, idx);
  statse_kernel<<<512, 256, 0, stream>>>(pos, idx, dstats);
  finalize1_kernel<<<1, 64, 0, stream>>>(dstats, W1, b1, g1, be1, scale1, shift1);
  edge2_kernel<<<EDGE2_GRID, 256, 0, stream>>>(pos, idx, W1, b1, scale1, shift1, W2, b2, am, eg_part);
  finalize2_kernel<<<C2, 256, 0, stream>>>(eg_part, g2, be2, scale2, shift2);
  gram_part_kernel<<<GRAM_GRID, 256, 0, stream>>>(am, scale2, shift2, gram_part);
  gram_reduce_kernel<<<(GRAM_ELEMS + 255) / 256, 256, 0, stream>>>(gram_part, G2, nodesum);
  finalize3_kernel<<<EMB, 128, 0, stream>>>(G2, nodesum, W3, b3, g3, be3, scale3, shift3);
  apply3pool_kernel<<<dim3(1024, 2), 256, 0, stream>>>(am, scale2, shift2, W3, b3, scale3, shift3, pp, psb);
  poolreduce_kernel<<<NB * EMB / 256, 256, 0, stream>>>(pp, psb, pooledmax, pooledsum);
  final_kernel<<<NB, 64, 0, stream>>>(pooledmax, pooledsum, W4, b4, out);
}